// Round 18
// baseline (388.610 us; speedup 1.0000x reference)
//
#include <hip/hip_runtime.h>
#include <hip/hip_bf16.h>
#include <math.h>

#define NFR 128
#define IND 256
#define ONODES 512

static constexpr float SM_SCALE = 0.08838834764831845f; // 128^-0.5

typedef __attribute__((ext_vector_type(8))) short bf16x8;
typedef __attribute__((ext_vector_type(4))) float f32x4;
typedef __attribute__((ext_vector_type(8))) unsigned short ushort8;
typedef __attribute__((ext_vector_type(4))) unsigned short ushort4v;

__device__ __forceinline__ unsigned short f2bf(float f){
    unsigned int b = __float_as_uint(f);
    b = (b + 0x7fffu + ((b >> 16) & 1u)) >> 16;
    return (unsigned short)b;
}
__device__ __forceinline__ float bf2f(unsigned short u){
    return __uint_as_float(((unsigned int)u) << 16);
}

// ---------------- G[m] = W_m * W_m^T (256x256) via bf16 MFMA; bf16 output.
__global__ __launch_bounds__(512) void kG(const float* __restrict__ w1, const float* __restrict__ w2,
                                          unsigned short* __restrict__ Gb){
    int m = blockIdx.x;
    const float* W; int K;
    if (m < NFR){ W = w1 + (size_t)m * IND * IND; K = IND; }
    else        { W = w2 + (size_t)(m - NFR) * IND * ONODES; K = ONODES; }
    __shared__ unsigned short Wt[256 * 64];
    int t = threadIdx.x;
    int w = t >> 6, l = t & 63;
    int wr = (w >> 2) * 128, wc = (w & 3) * 64;
    f32x4 acc[8][4] = {};
    int srow = t >> 3, sg = t & 7;
    for (int kb = 0; kb < K; kb += 64){
        __syncthreads();
        #pragma unroll
        for (int i = 0; i < 4; ++i){
            int row = i * 64 + srow;
            int dstg = sg ^ (row & 7);
            const float* src = &W[(size_t)row * K + kb + sg * 8];
            float4 f0 = *(const float4*)src;
            float4 f1 = *(const float4*)(src + 4);
            ushort8 v;
            v[0] = f2bf(f0.x); v[1] = f2bf(f0.y); v[2] = f2bf(f0.z); v[3] = f2bf(f0.w);
            v[4] = f2bf(f1.x); v[5] = f2bf(f1.y); v[6] = f2bf(f1.z); v[7] = f2bf(f1.w);
            *(ushort8*)&Wt[row * 64 + dstg * 8] = v;
        }
        __syncthreads();
        #pragma unroll
        for (int kh = 0; kh < 2; ++kh){
            bf16x8 af[8], bfr[4];
            #pragma unroll
            for (int fi = 0; fi < 8; ++fi){
                int row = wr + fi * 16 + (l & 15);
                int g = (kh * 4 + (l >> 4)) ^ (row & 7);
                af[fi] = *(const bf16x8*)&Wt[row * 64 + g * 8];
            }
            #pragma unroll
            for (int fj = 0; fj < 4; ++fj){
                int row = wc + fj * 16 + (l & 15);
                int g = (kh * 4 + (l >> 4)) ^ (row & 7);
                bfr[fj] = *(const bf16x8*)&Wt[row * 64 + g * 8];
            }
            #pragma unroll
            for (int fi = 0; fi < 8; ++fi)
                #pragma unroll
                for (int fj = 0; fj < 4; ++fj)
                    acc[fi][fj] = __builtin_amdgcn_mfma_f32_16x16x32_bf16(af[fi], bfr[fj], acc[fi][fj], 0, 0, 0);
        }
    }
    unsigned short* Gm = Gb + (size_t)m * 65536;
    #pragma unroll
    for (int fi = 0; fi < 8; ++fi){
        #pragma unroll
        for (int r = 0; r < 4; ++r){
            int n = wr + fi * 16 + (l >> 4) * 4 + r;
            unsigned short* grow = Gm + (size_t)n * 256 + wc + (l & 15);
            #pragma unroll
            for (int fj = 0; fj < 4; ++fj) grow[fj * 16] = f2bf(acc[fi][fj][r]);
        }
    }
}

// ---------------- G2[m] = G[m] * G[m] (bf16 in/out)
__global__ __launch_bounds__(512) void kG2(const unsigned short* __restrict__ Gb,
                                           unsigned short* __restrict__ G2b){
    int m = blockIdx.x;
    const unsigned short* Gm = Gb + (size_t)m * 65536;
    __shared__ unsigned short Wt[256 * 64];
    int t = threadIdx.x;
    int w = t >> 6, l = t & 63;
    int wr = (w >> 2) * 128, wc = (w & 3) * 64;
    f32x4 acc[8][4] = {};
    int srow = t >> 3, sg = t & 7;
    for (int kb = 0; kb < 256; kb += 64){
        __syncthreads();
        #pragma unroll
        for (int i = 0; i < 4; ++i){
            int row = i * 64 + srow;
            int dstg = sg ^ (row & 7);
            ushort8 v = *(const ushort8*)&Gm[(size_t)row * 256 + kb + sg * 8];
            *(ushort8*)&Wt[row * 64 + dstg * 8] = v;
        }
        __syncthreads();
        #pragma unroll
        for (int kh = 0; kh < 2; ++kh){
            bf16x8 af[8], bfr[4];
            #pragma unroll
            for (int fi = 0; fi < 8; ++fi){
                int row = wr + fi * 16 + (l & 15);
                int g = (kh * 4 + (l >> 4)) ^ (row & 7);
                af[fi] = *(const bf16x8*)&Wt[row * 64 + g * 8];
            }
            #pragma unroll
            for (int fj = 0; fj < 4; ++fj){
                int row = wc + fj * 16 + (l & 15);
                int g = (kh * 4 + (l >> 4)) ^ (row & 7);
                bfr[fj] = *(const bf16x8*)&Wt[row * 64 + g * 8];
            }
            #pragma unroll
            for (int fi = 0; fi < 8; ++fi)
                #pragma unroll
                for (int fj = 0; fj < 4; ++fj)
                    acc[fi][fj] = __builtin_amdgcn_mfma_f32_16x16x32_bf16(af[fi], bfr[fj], acc[fi][fj], 0, 0, 0);
        }
    }
    unsigned short* Om = G2b + (size_t)m * 65536;
    #pragma unroll
    for (int fi = 0; fi < 8; ++fi){
        #pragma unroll
        for (int r = 0; r < 4; ++r){
            int n = wr + fi * 16 + (l >> 4) * 4 + r;
            unsigned short* grow = Om + (size_t)n * 256 + wc + (l & 15);
            #pragma unroll
            for (int fj = 0; fj < 4; ++fj) grow[fj * 16] = f2bf(acc[fi][fj][r]);
        }
    }
}

// ---------------- power iteration on G2 (64 iters == 128 on G), deferred normalization.
// G2 staged ONCE into LDS (XOR-granule swizzle) -> per-iter fragment reads hit LDS (69 TB/s)
// instead of the L2 re-stream the compiler forced (R8-R11: fragments never stayed resident).
// Same arithmetic/order as R17 -> bitwise identical result.
__global__ __launch_bounds__(512, 1) void kP3(const float* __restrict__ w1, const float* __restrict__ w2,
                                              const unsigned short* __restrict__ G2b, float* __restrict__ inv_s){
    __shared__ unsigned short G2L[65536];   // 131072 B, row-major 256/row, granule-swizzled
    __shared__ unsigned short XT[8192];     // two 8KB X buffers (4096 ushorts each)
    __shared__ float red[24];
    int m = blockIdx.x, t = threadIdx.x;
    int w = t >> 6, l = t & 63;
    int mrow = l & 15, kq = l >> 4;
    const unsigned short* Gm = G2b + (size_t)m * 65536;
    // stage G2: row r, 16B-granule g8 stored at r*256 + ((g8 ^ (r&7))*8)
    for (int i = t; i < 8192; i += 512){
        int r = i >> 5, g8 = i & 31;
        ushort8 v = *(const ushort8*)&Gm[(size_t)r * 256 + g8 * 8];
        *(ushort8*)&G2L[r * 256 + ((g8 ^ (r & 7)) * 8)] = v;
    }
    if (t < 256){
        unsigned int h = (unsigned int)t * 2654435761u ^ 0x9e3779b9u;
        h ^= h >> 13; h *= 0x85ebca6bu; h ^= h >> 16;
        unsigned short xb = f2bf(0.5f + (float)(h & 0xffffu) * (1.0f / 65536.0f));
        #pragma unroll
        for (int c = 0; c < 16; ++c)
            XT[c * 256 + (t ^ ((c & 7) << 3))] = xb;
    }
    __syncthreads();
    int r0a = w * 32 + mrow, r1a = w * 32 + 16 + mrow;
    int cur = 0;
    for (int it = 0; it < 64; ++it){
        const unsigned short* Xc = &XT[cur * 4096];
        unsigned short* Xn = &XT[(cur ^ 1) * 4096];
        bf16x8 bq[8];
        #pragma unroll
        for (int ks = 0; ks < 8; ++ks)
            bq[ks] = *(const bf16x8*)&Xc[mrow * 256 + ((ks * 32 + kq * 8) ^ ((mrow & 7) << 3))];
        f32x4 acc0 = {}, acc1 = {};
        #pragma unroll
        for (int ks = 0; ks < 8; ++ks){
            bf16x8 a0 = *(const bf16x8*)&G2L[r0a * 256 + (((ks * 4 + kq) ^ (r0a & 7)) * 8)];
            bf16x8 a1 = *(const bf16x8*)&G2L[r1a * 256 + (((ks * 4 + kq) ^ (r1a & 7)) * 8)];
            acc0 = __builtin_amdgcn_mfma_f32_16x16x32_bf16(a0, bq[ks], acc0, 0, 0, 0);
            acc1 = __builtin_amdgcn_mfma_f32_16x16x32_bf16(a1, bq[ks], acc1, 0, 0, 0);
        }
        int r0 = w * 32 + kq * 4;
        if ((it & 3) == 3){
            float ss = 0.f;
            if (mrow == 0){
                #pragma unroll
                for (int r = 0; r < 4; ++r) ss += acc0[r] * acc0[r] + acc1[r] * acc1[r];
            }
            #pragma unroll
            for (int off = 1; off < 64; off <<= 1) ss += __shfl_xor(ss, off);
            if (l == 0) red[w] = ss;
            __syncthreads();
            float rs = rsqrtf(red[0] + red[1] + red[2] + red[3] + red[4] + red[5] + red[6] + red[7]);
            ushort4v v0, v1;
            #pragma unroll
            for (int r = 0; r < 4; ++r){ v0[r] = f2bf(acc0[r] * rs); v1[r] = f2bf(acc1[r] * rs); }
            *(ushort4v*)&Xn[mrow * 256 + (r0 ^ ((mrow & 7) << 3))] = v0;
            *(ushort4v*)&Xn[mrow * 256 + ((r0 + 16) ^ ((mrow & 7) << 3))] = v1;
            __syncthreads();
        } else {
            ushort4v v0, v1;
            #pragma unroll
            for (int r = 0; r < 4; ++r){ v0[r] = f2bf(acc0[r] * 65536.0f); v1[r] = f2bf(acc1[r] * 65536.0f); }
            *(ushort4v*)&Xn[mrow * 256 + (r0 ^ ((mrow & 7) << 3))] = v0;
            *(ushort4v*)&Xn[mrow * 256 + ((r0 + 16) ^ ((mrow & 7) << 3))] = v1;
            __syncthreads();
        }
        cur ^= 1;
    }
    const unsigned short* Xf = &XT[cur * 4096];
    const float* W; int K;
    if (m < NFR){ W = w1 + (size_t)m * IND * IND; K = IND; }
    else        { W = w2 + (size_t)(m - NFR) * IND * ONODES; K = ONODES; }
    float zsq = 0.f;
    for (int o = t; o < K; o += 512){
        float z = 0.f;
        for (int d = 0; d < 256; ++d) z += W[(size_t)d * K + o] * bf2f(Xf[d]);
        zsq += z * z;
    }
    #pragma unroll
    for (int off = 1; off < 64; off <<= 1) zsq += __shfl_xor(zsq, off);
    if (l == 0) red[8 + w] = zsq;
    float xsq = 0.f;
    if (t < 256){
        float xd = bf2f(Xf[t]);
        xsq = xd * xd;
    }
    #pragma unroll
    for (int off = 1; off < 64; off <<= 1) xsq += __shfl_xor(xsq, off);
    if (l == 0) red[16 + w] = xsq;
    __syncthreads();
    if (t == 0){
        float num = 0.f, den = 0.f;
        #pragma unroll
        for (int i = 0; i < 8; ++i){ num += red[8 + i]; den += red[16 + i]; }
        float sg = sqrtf(fmaxf(num / fmaxf(den, 1e-20f), 0.f));
        inv_s[m] = 1.0f / fmaxf(sg, 1e-6f);
    }
}

// ---------------- per-frame MLP, 2 blocks/frame (8 batches each)
__global__ __launch_bounds__(256) void kMLP(const float* __restrict__ inp, const float* __restrict__ w1,
                                            const float* __restrict__ b1, const float* __restrict__ w2,
                                            const float* __restrict__ b2, const float* __restrict__ inv_s,
                                            float* __restrict__ nf, unsigned short* __restrict__ nfb){
    int n = blockIdx.x >> 1, b0 = (blockIdx.x & 1) * 8, t = threadIdx.x;
    __shared__ float xl[8][IND];
    __shared__ float hl[8][IND];
    float i1 = inv_s[n], i2 = inv_s[NFR + n];
    for (int i = t; i < 8 * IND; i += 256){
        int b = i >> 8, d = i & 255;
        xl[b][d] = inp[(size_t)(b0 + b) * (NFR * IND) + (size_t)n * IND + d];
    }
    __syncthreads();
    const float* W1 = w1 + (size_t)n * IND * IND;
    float acc[8] = {};
    for (int d = 0; d < IND; ++d){
        float w = W1[(size_t)d * IND + t];
        #pragma unroll
        for (int b = 0; b < 8; ++b) acc[b] += xl[b][d] * w;
    }
    float bb = b1[(size_t)n * IND + t];
    #pragma unroll
    for (int b = 0; b < 8; ++b){
        float h = acc[b] * i1 + bb;
        h = 0.5f * h * (1.0f + erff(h * 0.70710678118654752f));
        hl[b][t] = h;
    }
    __syncthreads();
    const float* W2 = w2 + (size_t)n * IND * ONODES;
    float o0[8] = {}, o1[8] = {};
    for (int d = 0; d < IND; ++d){
        float wa = W2[(size_t)d * ONODES + t];
        float wb = W2[(size_t)d * ONODES + t + 256];
        #pragma unroll
        for (int b = 0; b < 8; ++b){ float h = hl[b][d]; o0[b] += h * wa; o1[b] += h * wb; }
    }
    float bb0 = b2[(size_t)n * ONODES + t], bb1 = b2[(size_t)n * ONODES + t + 256];
    #pragma unroll
    for (int b = 0; b < 8; ++b){
        float r0 = o0[b] * i2 + bb0;
        float r1 = o1[b] * i2 + bb1;
        size_t bb_ = (size_t)(b0 + b) * (ONODES * NFR);
        nf[bb_ + (size_t)t * NFR + n]         = r0;
        nf[bb_ + (size_t)(t + 256) * NFR + n] = r1;
        nfb[bb_ + (size_t)t * NFR + n]         = f2bf(r0);
        nfb[bb_ + (size_t)(t + 256) * NFR + n] = f2bf(r1);
    }
}

// ---------------- transpose wqk [128][2048] fp32 -> wqkT [2048][128] bf16
__global__ __launch_bounds__(256) void kWT(const float* __restrict__ wqk, unsigned short* __restrict__ wqkT){
    int j = blockIdx.x * 256 + threadIdx.x;
    unsigned short* dst = wqkT + (size_t)j * 128;
    #pragma unroll
    for (int fb = 0; fb < 16; ++fb){
        ushort8 v;
        #pragma unroll
        for (int u = 0; u < 8; ++u) v[u] = f2bf(wqk[(size_t)(fb * 8 + u) * 2048 + j]);
        *(ushort8*)&dst[fb * 8] = v;
    }
}

// ---------------- qk projection via SWAPPED bf16 MFMA: packed 8B stores
__global__ __launch_bounds__(256) void kQK2(const unsigned short* __restrict__ nfb,
                                            const unsigned short* __restrict__ wqkT,
                                            unsigned short* __restrict__ qb, unsigned short* __restrict__ kb){
    int b = blockIdx.x, rb = blockIdx.y, jt = blockIdx.z;
    int t = threadIdx.x, w = t >> 6, l = t & 63;
    int mrow = l & 15, kq = l >> 4;
    const unsigned short* A = nfb + ((size_t)b * 512 + rb * 64) * 128;
    const unsigned short* B = wqkT + (size_t)(jt * 512 + w * 128) * 128;
    int jbase = jt * 512 + w * 128;
    int s = jbase >> 10, c = (jbase >> 7) & 7;
    unsigned short* out = (s ? kb : qb) + ((size_t)(b * 8 + c) * 512) * 128;
    f32x4 acc[4][8];
    #pragma unroll
    for (int fi = 0; fi < 4; ++fi)
        #pragma unroll
        for (int fj = 0; fj < 8; ++fj) acc[fi][fj] = (f32x4){0.f, 0.f, 0.f, 0.f};
    #pragma unroll
    for (int kh = 0; kh < 4; ++kh){
        bf16x8 bfr[8];
        #pragma unroll
        for (int fj = 0; fj < 8; ++fj)
            bfr[fj] = *(const bf16x8*)&B[(size_t)(fj * 16 + mrow) * 128 + kh * 32 + kq * 8];
        #pragma unroll
        for (int fi = 0; fi < 4; ++fi){
            bf16x8 af = *(const bf16x8*)&A[(size_t)(fi * 16 + mrow) * 128 + kh * 32 + kq * 8];
            #pragma unroll
            for (int fj = 0; fj < 8; ++fj)
                acc[fi][fj] = __builtin_amdgcn_mfma_f32_16x16x32_bf16(bfr[fj], af, acc[fi][fj], 0, 0, 0);
        }
    }
    #pragma unroll
    for (int fi = 0; fi < 4; ++fi){
        int node = rb * 64 + fi * 16 + mrow;
        unsigned short* dst = out + (size_t)node * 128 + kq * 4;
        #pragma unroll
        for (int fj = 0; fj < 8; ++fj){
            ushort4v v;
            #pragma unroll
            for (int r = 0; r < 4; ++r) v[r] = f2bf(acc[fi][fj][r]);
            *(ushort4v*)&dst[fj * 16] = v;
        }
    }
}

// ---------------- scores via SWAPPED MFMA (K*Q^T = S^T fragments) + softmax -> attn bf16
__global__ __launch_bounds__(256) void kS2(const unsigned short* __restrict__ qb,
                                           const unsigned short* __restrict__ kb,
                                           unsigned short* __restrict__ attnb){
    int b = blockIdx.x, c = blockIdx.y, rb = blockIdx.z;
    int t = threadIdx.x, w = t >> 6, l = t & 63;
    int mrow = l & 15, kq = l >> 4;
    size_t bc = (size_t)(b * 8 + c) * 512;
    const unsigned short* Q  = qb + (bc + rb * 64) * 128;
    const unsigned short* Kp = kb + (bc + w * 128) * 128;
    __shared__ float rmax[4][64];
    __shared__ float rsum[4][64];
    f32x4 acc[4][8];
    #pragma unroll
    for (int fi = 0; fi < 4; ++fi)
        #pragma unroll
        for (int fj = 0; fj < 8; ++fj) acc[fi][fj] = (f32x4){0.f, 0.f, 0.f, 0.f};
    #pragma unroll
    for (int kh = 0; kh < 4; ++kh){
        bf16x8 kfr[8];
        #pragma unroll
        for (int fj = 0; fj < 8; ++fj)
            kfr[fj] = *(const bf16x8*)&Kp[(size_t)(fj * 16 + mrow) * 128 + kh * 32 + kq * 8];
        #pragma unroll
        for (int fi = 0; fi < 4; ++fi){
            bf16x8 qf = *(const bf16x8*)&Q[(size_t)(fi * 16 + mrow) * 128 + kh * 32 + kq * 8];
            #pragma unroll
            for (int fj = 0; fj < 8; ++fj)
                acc[fi][fj] = __builtin_amdgcn_mfma_f32_16x16x32_bf16(kfr[fj], qf, acc[fi][fj], 0, 0, 0);
        }
    }
    #pragma unroll
    for (int fi = 0; fi < 4; ++fi){
        float mx = acc[fi][0][0];
        #pragma unroll
        for (int fj = 0; fj < 8; ++fj)
            #pragma unroll
            for (int r = 0; r < 4; ++r) mx = fmaxf(mx, acc[fi][fj][r]);
        mx = fmaxf(mx, __shfl_xor(mx, 16));
        mx = fmaxf(mx, __shfl_xor(mx, 32));
        if (kq == 0) rmax[w][fi * 16 + mrow] = mx;
    }
    __syncthreads();
    #pragma unroll
    for (int fi = 0; fi < 4; ++fi){
        int ql = fi * 16 + mrow;
        float gm = fmaxf(fmaxf(rmax[0][ql], rmax[1][ql]), fmaxf(rmax[2][ql], rmax[3][ql]));
        float s = 0.f;
        #pragma unroll
        for (int fj = 0; fj < 8; ++fj)
            #pragma unroll
            for (int r = 0; r < 4; ++r){
                float p = __expf((acc[fi][fj][r] - gm) * SM_SCALE);
                acc[fi][fj][r] = p;
                s += p;
            }
        s += __shfl_xor(s, 16);
        s += __shfl_xor(s, 32);
        if (kq == 0) rsum[w][ql] = s;
    }
    __syncthreads();
    #pragma unroll
    for (int fi = 0; fi < 4; ++fi){
        int ql = fi * 16 + mrow;
        float inv = 1.0f / (rsum[0][ql] + rsum[1][ql] + rsum[2][ql] + rsum[3][ql]);
        size_t rowb = (bc + rb * 64 + ql) * 512 + w * 128 + kq * 4;
        #pragma unroll
        for (int fj = 0; fj < 8; ++fj){
            ushort4v v;
            #pragma unroll
            for (int r = 0; r < 4; ++r) v[r] = f2bf(acc[fi][fj][r] * inv);
            *(ushort4v*)&attnb[rowb + fj * 16] = v;
        }
    }
}

// ---------------- fused: channel-sum radix-select top-32 + diag -> mask -> row-normalize -> bf16 NR
__global__ __launch_bounds__(256) void kTN(const unsigned short* __restrict__ attnb, unsigned short* __restrict__ nrb){
    int b = blockIdx.x >> 9, n = blockIdx.x & 511;
    int t = threadIdx.x, w = t >> 6, lane = t & 63;
    __shared__ unsigned short al[8][512];
    __shared__ unsigned long long keepm[8];
    ushort8* alv = (ushort8*)&al[0][0];
    for (int i = t; i < 512; i += 256){
        int c = i >> 6, o = i & 63;
        alv[i] = *(const ushort8*)&attnb[((size_t)(b * 8 + c) * 512 + n) * 512 + o * 8];
    }
    __syncthreads();
    if (w == 0){
        unsigned int vb[8];
        #pragma unroll
        for (int j = 0; j < 8; ++j){
            float s = 0.f;
            #pragma unroll
            for (int c = 0; c < 8; ++c) s += bf2f(al[c][j * 64 + lane]);
            vb[j] = __float_as_uint(s);
        }
        unsigned int T = 0u;
        for (int bit = 31; bit >= 0; --bit){
            unsigned int cand = T | (1u << bit);
            int cnt = 0;
            #pragma unroll
            for (int j = 0; j < 8; ++j) cnt += __popcll(__ballot(vb[j] >= cand));
            if (cnt >= 32) T = cand;
        }
        int cntgt = 0;
        #pragma unroll
        for (int j = 0; j < 8; ++j) cntgt += __popcll(__ballot(vb[j] > T));
        int need = 32 - cntgt;
        unsigned long long lmask = (1ull << lane) - 1ull;
        int run = 0;
        #pragma unroll
        for (int j = 0; j < 8; ++j){
            bool eq = (vb[j] == T);
            unsigned long long eqm = __ballot(eq);
            int rank = run + __popcll(eqm & lmask);
            bool kv = (vb[j] > T) || (eq && rank < need);
            unsigned long long km = __ballot(kv);
            if (lane == 0) keepm[j] = km;
            run += __popcll(eqm);
        }
    }
    __syncthreads();
    #pragma unroll
    for (int cc = 0; cc < 2; ++cc){
        int c = w * 2 + cc;
        float e[8]; float rs = 0.f;
        #pragma unroll
        for (int j = 0; j < 8; ++j){
            float a = bf2f(al[c][j * 64 + lane]);
            bool keep = ((keepm[j] >> lane) & 1ull) || (j * 64 + lane == n);
            e[j] = keep ? a : 0.0f;
            rs += e[j];
        }
        #pragma unroll
        for (int off = 1; off < 64; off <<= 1) rs += __shfl_xor(rs, off);
        float inv = 1.0f / (rs + 1e-6f);
        size_t base = ((size_t)(b * 8 + c) * 512 + n) * 512;
        #pragma unroll
        for (int j = 0; j < 8; ++j) nrb[base + j * 64 + lane] = f2bf(e[j] * inv);
    }
}

// ---------------- column sums of NR (bf16 in, fp32 out), ushort8-vectorized
__global__ __launch_bounds__(1024) void kC(const unsigned short* __restrict__ nrb, float* __restrict__ cs){
    int b = blockIdx.x, c = blockIdx.y, t = threadIdx.x;
    int mg = (t & 63) * 8;
    int nh = t >> 6;
    const unsigned short* Mp = nrb + (size_t)(b * 8 + c) * 262144;
    float s[8] = {};
    for (int n = nh * 32; n < nh * 32 + 32; ++n){
        ushort8 v = *(const ushort8*)&Mp[(size_t)n * 512 + mg];
        #pragma unroll
        for (int j = 0; j < 8; ++j) s[j] += bf2f(v[j]);
    }
    __shared__ float red[16][512];
    #pragma unroll
    for (int j = 0; j < 8; ++j) red[nh][mg + j] = s[j];
    __syncthreads();
    if (t < 512){
        float tot = 0.f;
        #pragma unroll
        for (int i = 0; i < 16; ++i) tot += red[i][t];
        cs[(size_t)(b * 8 + c) * 512 + t] = tot;
    }
}

// ---------------- out = (NR*D) * NR^T per (b,c), one-sided D; swapped MFMA; 128x256 tiles.
__global__ __launch_bounds__(256, 2) void kF(const unsigned short* __restrict__ S, const float* __restrict__ cs,
                                             float* __restrict__ oe){
    int b = blockIdx.x, c = blockIdx.y, tz = blockIdx.z;
    int nb = (tz >> 1) * 128, mb = (tz & 1) * 256;
    size_t bc = (size_t)(b * 8 + c) * 512;
    const unsigned short* M = S + bc * 512;
    __shared__ unsigned short At[128 * 64];
    __shared__ unsigned short Bt[256 * 64];
    __shared__ float dl[512];
    int t = threadIdx.x;
    for (int i = t; i < 512; i += 256){ float v = cs[bc + i]; dl[i] = 1.0f / (v + 1e-6f); }
    int w = t >> 6, l = t & 63;
    int wr = (w & 1) * 64, wc = (w >> 1) * 128;
    f32x4 acc[4][8];
    #pragma unroll
    for (int fi = 0; fi < 4; ++fi)
        #pragma unroll
        for (int fj = 0; fj < 8; ++fj) acc[fi][fj] = (f32x4){0.f, 0.f, 0.f, 0.f};
    int srow = t >> 3, sg = t & 7;
    int mrow = l & 15, kq = l >> 4;
    __syncthreads();
    for (int kb = 0; kb < 512; kb += 64){
        __syncthreads();
        float4 d0 = *(const float4*)&dl[kb + sg * 8];
        float4 d1 = *(const float4*)&dl[kb + sg * 8 + 4];
        float dv[8] = {d0.x, d0.y, d0.z, d0.w, d1.x, d1.y, d1.z, d1.w};
        #pragma unroll
        for (int i = 0; i < 4; ++i){
            int row = i * 32 + srow;
            int dstg = sg ^ (row & 7);
            ushort8 va = *(const ushort8*)&M[(size_t)(nb + row) * 512 + kb + sg * 8];
            ushort8 wa;
            #pragma unroll
            for (int j = 0; j < 8; ++j) wa[j] = f2bf(bf2f(va[j]) * dv[j]);
            *(ushort8*)&At[row * 64 + dstg * 8] = wa;
        }
        #pragma unroll
        for (int i = 0; i < 8; ++i){
            int row = i * 32 + srow;
            int dstg = sg ^ (row & 7);
            ushort8 vb = *(const ushort8*)&M[(size_t)(mb + row) * 512 + kb + sg * 8];
            *(ushort8*)&Bt[row * 64 + dstg * 8] = vb;
        }
        __syncthreads();
        #pragma unroll
        for (int kh = 0; kh < 2; ++kh){
            bf16x8 af[4], bfr[8];
            #pragma unroll
            for (int fi = 0; fi < 4; ++fi){
                int row = wr + fi * 16 + mrow;
                int g = (kh * 4 + kq) ^ (row & 7);
                af[fi] = *(const bf16x8*)&At[row * 64 + g * 8];
            }
            #pragma unroll
            for (int fj = 0; fj < 8; ++fj){
                int row = wc + fj * 16 + mrow;
                int g = (kh * 4 + kq) ^ (row & 7);
                bfr[fj] = *(const bf16x8*)&Bt[row * 64 + g * 8];
            }
            #pragma unroll
            for (int fi = 0; fi < 4; ++fi)
                #pragma unroll
                for (int fj = 0; fj < 8; ++fj)
                    acc[fi][fj] = __builtin_amdgcn_mfma_f32_16x16x32_bf16(bfr[fj], af[fi], acc[fi][fj], 0, 0, 0);
        }
    }
    #pragma unroll
    for (int fi = 0; fi < 4; ++fi){
        int n = nb + wr + fi * 16 + mrow;
        float* orow = oe + (bc + n) * 512 + mb + wc + kq * 4;
        #pragma unroll
        for (int fj = 0; fj < 8; ++fj)
            *(float4*)&orow[fj * 16] = make_float4(acc[fi][fj][0], acc[fi][fj][1], acc[fi][fj][2], acc[fi][fj][3]);
    }
}

extern "C" void kernel_launch(void* const* d_in, const int* in_sizes, int n_in,
                              void* d_out, int out_size, void* d_ws, size_t ws_size,
                              hipStream_t stream) {
    const float* inp = (const float*)d_in[0];
    const float* w1  = (const float*)d_in[1];
    const float* b1  = (const float*)d_in[2];
    const float* w2  = (const float*)d_in[3];
    const float* b2  = (const float*)d_in[4];
    const float* wqk = (const float*)d_in[5];

    float* out_nf   = (float*)d_out;                       // [16][512][128]
    float* out_edge = out_nf + (size_t)16 * 512 * 128;     // [16][8][512][512]

    char* ws = (char*)d_ws;
    float* inv_s = (float*)ws;                             // 256 floats
    // region A (134 MB): q/k bf16 during kQK2/kS2, then reused as bf16 NR
    unsigned short* qb  = (unsigned short*)(ws + 4096);            // [16][8][512][128] bf16
    unsigned short* kbuf = qb + (size_t)16 * 8 * 512 * 128;        // [16][8][512][128] bf16
    unsigned short* nrb = qb;                                       // [16][8][512][512] bf16 (aliases q+k)
    // region B (134 MB): attn bf16; G/G2 alias it (dead before attn written)
    unsigned short* attnb = (unsigned short*)(ws + 4096 + (size_t)134 * 1024 * 1024);
    unsigned short* Gb  = attnb;                                    // [256][256][256] bf16 (33.5 MB)
    unsigned short* G2b = Gb + (size_t)256 * 65536;                 // [256][256][256] bf16 (33.5 MB)
    float* csum = (float*)(attnb + (size_t)16 * 8 * 512 * 512);    // [16][8][512]
    unsigned short* nfb  = (unsigned short*)(csum + (size_t)16 * 8 * 512);  // [16][512][128] bf16 (2 MB)
    unsigned short* wqkT = nfb + (size_t)16 * 512 * 128;                    // [2048][128] bf16 (0.5 MB)

    kG  <<<256, 512, 0, stream>>>(w1, w2, Gb);
    kG2 <<<256, 512, 0, stream>>>(Gb, G2b);
    kP3 <<<256, 512, 0, stream>>>(w1, w2, G2b, inv_s);
    kMLP<<<256, 256, 0, stream>>>(inp, w1, b1, w2, b2, inv_s, out_nf, nfb);
    kWT <<<8, 256, 0, stream>>>(wqk, wqkT);
    kQK2<<<dim3(16, 8, 4), 256, 0, stream>>>(nfb, wqkT, qb, kbuf);
    kS2 <<<dim3(16, 8, 8), 256, 0, stream>>>(qb, kbuf, attnb);
    kTN <<<8192, 256, 0, stream>>>(attnb, nrb);
    kC  <<<dim3(16, 8), 1024, 0, stream>>>(nrb, csum);
    kF  <<<dim3(16, 8, 8), 256, 0, stream>>>(nrb, csum, out_edge);
}

// Round 19
// 364.624 us; speedup vs baseline: 1.0658x; 1.0658x over previous
//
#include <hip/hip_runtime.h>
#include <hip/hip_bf16.h>
#include <math.h>

#define NFR 128
#define IND 256
#define ONODES 512

static constexpr float SM_SCALE = 0.08838834764831845f; // 128^-0.5

typedef __attribute__((ext_vector_type(8))) short bf16x8;
typedef __attribute__((ext_vector_type(4))) float f32x4;
typedef __attribute__((ext_vector_type(8))) unsigned short ushort8;
typedef __attribute__((ext_vector_type(4))) unsigned short ushort4v;

__device__ __forceinline__ unsigned short f2bf(float f){
    unsigned int b = __float_as_uint(f);
    b = (b + 0x7fffu + ((b >> 16) & 1u)) >> 16;
    return (unsigned short)b;
}
__device__ __forceinline__ float bf2f(unsigned short u){
    return __uint_as_float(((unsigned int)u) << 16);
}

// ---------------- G[m] = W_m * W_m^T (256x256) via bf16 MFMA; bf16 output.
__global__ __launch_bounds__(512) void kG(const float* __restrict__ w1, const float* __restrict__ w2,
                                          unsigned short* __restrict__ Gb){
    int m = blockIdx.x;
    const float* W; int K;
    if (m < NFR){ W = w1 + (size_t)m * IND * IND; K = IND; }
    else        { W = w2 + (size_t)(m - NFR) * IND * ONODES; K = ONODES; }
    __shared__ unsigned short Wt[256 * 64];
    int t = threadIdx.x;
    int w = t >> 6, l = t & 63;
    int wr = (w >> 2) * 128, wc = (w & 3) * 64;
    f32x4 acc[8][4] = {};
    int srow = t >> 3, sg = t & 7;
    for (int kb = 0; kb < K; kb += 64){
        __syncthreads();
        #pragma unroll
        for (int i = 0; i < 4; ++i){
            int row = i * 64 + srow;
            int dstg = sg ^ (row & 7);
            const float* src = &W[(size_t)row * K + kb + sg * 8];
            float4 f0 = *(const float4*)src;
            float4 f1 = *(const float4*)(src + 4);
            ushort8 v;
            v[0] = f2bf(f0.x); v[1] = f2bf(f0.y); v[2] = f2bf(f0.z); v[3] = f2bf(f0.w);
            v[4] = f2bf(f1.x); v[5] = f2bf(f1.y); v[6] = f2bf(f1.z); v[7] = f2bf(f1.w);
            *(ushort8*)&Wt[row * 64 + dstg * 8] = v;
        }
        __syncthreads();
        #pragma unroll
        for (int kh = 0; kh < 2; ++kh){
            bf16x8 af[8], bfr[4];
            #pragma unroll
            for (int fi = 0; fi < 8; ++fi){
                int row = wr + fi * 16 + (l & 15);
                int g = (kh * 4 + (l >> 4)) ^ (row & 7);
                af[fi] = *(const bf16x8*)&Wt[row * 64 + g * 8];
            }
            #pragma unroll
            for (int fj = 0; fj < 4; ++fj){
                int row = wc + fj * 16 + (l & 15);
                int g = (kh * 4 + (l >> 4)) ^ (row & 7);
                bfr[fj] = *(const bf16x8*)&Wt[row * 64 + g * 8];
            }
            #pragma unroll
            for (int fi = 0; fi < 8; ++fi)
                #pragma unroll
                for (int fj = 0; fj < 4; ++fj)
                    acc[fi][fj] = __builtin_amdgcn_mfma_f32_16x16x32_bf16(af[fi], bfr[fj], acc[fi][fj], 0, 0, 0);
        }
    }
    unsigned short* Gm = Gb + (size_t)m * 65536;
    #pragma unroll
    for (int fi = 0; fi < 8; ++fi){
        #pragma unroll
        for (int r = 0; r < 4; ++r){
            int n = wr + fi * 16 + (l >> 4) * 4 + r;
            unsigned short* grow = Gm + (size_t)n * 256 + wc + (l & 15);
            #pragma unroll
            for (int fj = 0; fj < 4; ++fj) grow[fj * 16] = f2bf(acc[fi][fj][r]);
        }
    }
}

// ---------------- G2[m] = G[m] * G[m] (bf16 in/out)
__global__ __launch_bounds__(512) void kG2(const unsigned short* __restrict__ Gb,
                                           unsigned short* __restrict__ G2b){
    int m = blockIdx.x;
    const unsigned short* Gm = Gb + (size_t)m * 65536;
    __shared__ unsigned short Wt[256 * 64];
    int t = threadIdx.x;
    int w = t >> 6, l = t & 63;
    int wr = (w >> 2) * 128, wc = (w & 3) * 64;
    f32x4 acc[8][4] = {};
    int srow = t >> 3, sg = t & 7;
    for (int kb = 0; kb < 256; kb += 64){
        __syncthreads();
        #pragma unroll
        for (int i = 0; i < 4; ++i){
            int row = i * 64 + srow;
            int dstg = sg ^ (row & 7);
            ushort8 v = *(const ushort8*)&Gm[(size_t)row * 256 + kb + sg * 8];
            *(ushort8*)&Wt[row * 64 + dstg * 8] = v;
        }
        __syncthreads();
        #pragma unroll
        for (int kh = 0; kh < 2; ++kh){
            bf16x8 af[8], bfr[4];
            #pragma unroll
            for (int fi = 0; fi < 8; ++fi){
                int row = wr + fi * 16 + (l & 15);
                int g = (kh * 4 + (l >> 4)) ^ (row & 7);
                af[fi] = *(const bf16x8*)&Wt[row * 64 + g * 8];
            }
            #pragma unroll
            for (int fj = 0; fj < 4; ++fj){
                int row = wc + fj * 16 + (l & 15);
                int g = (kh * 4 + (l >> 4)) ^ (row & 7);
                bfr[fj] = *(const bf16x8*)&Wt[row * 64 + g * 8];
            }
            #pragma unroll
            for (int fi = 0; fi < 8; ++fi)
                #pragma unroll
                for (int fj = 0; fj < 4; ++fj)
                    acc[fi][fj] = __builtin_amdgcn_mfma_f32_16x16x32_bf16(af[fi], bfr[fj], acc[fi][fj], 0, 0, 0);
        }
    }
    unsigned short* Om = G2b + (size_t)m * 65536;
    #pragma unroll
    for (int fi = 0; fi < 8; ++fi){
        #pragma unroll
        for (int r = 0; r < 4; ++r){
            int n = wr + fi * 16 + (l >> 4) * 4 + r;
            unsigned short* grow = Om + (size_t)n * 256 + wc + (l & 15);
            #pragma unroll
            for (int fj = 0; fj < 4; ++fj) grow[fj * 16] = f2bf(acc[fi][fj][r]);
        }
    }
}

// ---------------- power iteration on G2 (64 iters == 128 on G), deferred normalization.
// (R17-proven version: pinned register fragments, oversized LDS for occupancy model,
//  every-4th normalization with exact pow2 rescale in between.)
__global__ __launch_bounds__(512, 1) void kP3(const float* __restrict__ w1, const float* __restrict__ w2,
                                              const unsigned short* __restrict__ G2b, float* __restrict__ inv_s){
    __shared__ unsigned short XT[43008];
    __shared__ float red[24];
    int m = blockIdx.x, t = threadIdx.x;
    int w = t >> 6, l = t & 63;
    int mrow = l & 15, kq = l >> 4;
    const unsigned short* Gm = G2b + (size_t)m * 65536;
    bf16x8 a0[8], a1[8];
    #pragma unroll
    for (int ks = 0; ks < 8; ++ks){
        a0[ks] = *(const bf16x8*)&Gm[(size_t)(w * 32 + mrow) * 256 + ks * 32 + kq * 8];
        a1[ks] = *(const bf16x8*)&Gm[(size_t)(w * 32 + 16 + mrow) * 256 + ks * 32 + kq * 8];
    }
    #pragma unroll
    for (int ks = 0; ks < 8; ++ks){
        asm volatile("" : "+v"(a0[ks]));
        asm volatile("" : "+v"(a1[ks]));
    }
    if (t < 256){
        unsigned int h = (unsigned int)t * 2654435761u ^ 0x9e3779b9u;
        h ^= h >> 13; h *= 0x85ebca6bu; h ^= h >> 16;
        unsigned short xb = f2bf(0.5f + (float)(h & 0xffffu) * (1.0f / 65536.0f));
        #pragma unroll
        for (int c = 0; c < 16; ++c)
            XT[c * 256 + (t ^ ((c & 7) << 3))] = xb;
    }
    __syncthreads();
    int cur = 0;
    for (int it = 0; it < 64; ++it){
        const unsigned short* Xc = &XT[cur * 4096];
        unsigned short* Xn = &XT[(cur ^ 1) * 4096];
        bf16x8 bq[8];
        #pragma unroll
        for (int ks = 0; ks < 8; ++ks)
            bq[ks] = *(const bf16x8*)&Xc[mrow * 256 + ((ks * 32 + kq * 8) ^ ((mrow & 7) << 3))];
        f32x4 acc0 = {}, acc1 = {};
        #pragma unroll
        for (int ks = 0; ks < 8; ++ks){
            acc0 = __builtin_amdgcn_mfma_f32_16x16x32_bf16(a0[ks], bq[ks], acc0, 0, 0, 0);
            acc1 = __builtin_amdgcn_mfma_f32_16x16x32_bf16(a1[ks], bq[ks], acc1, 0, 0, 0);
        }
        int r0 = w * 32 + kq * 4;
        if ((it & 3) == 3){
            float ss = 0.f;
            if (mrow == 0){
                #pragma unroll
                for (int r = 0; r < 4; ++r) ss += acc0[r] * acc0[r] + acc1[r] * acc1[r];
            }
            #pragma unroll
            for (int off = 1; off < 64; off <<= 1) ss += __shfl_xor(ss, off);
            if (l == 0) red[w] = ss;
            __syncthreads();
            float rs = rsqrtf(red[0] + red[1] + red[2] + red[3] + red[4] + red[5] + red[6] + red[7]);
            ushort4v v0, v1;
            #pragma unroll
            for (int r = 0; r < 4; ++r){ v0[r] = f2bf(acc0[r] * rs); v1[r] = f2bf(acc1[r] * rs); }
            *(ushort4v*)&Xn[mrow * 256 + (r0 ^ ((mrow & 7) << 3))] = v0;
            *(ushort4v*)&Xn[mrow * 256 + ((r0 + 16) ^ ((mrow & 7) << 3))] = v1;
            __syncthreads();
        } else {
            ushort4v v0, v1;
            #pragma unroll
            for (int r = 0; r < 4; ++r){ v0[r] = f2bf(acc0[r] * 65536.0f); v1[r] = f2bf(acc1[r] * 65536.0f); }
            *(ushort4v*)&Xn[mrow * 256 + (r0 ^ ((mrow & 7) << 3))] = v0;
            *(ushort4v*)&Xn[mrow * 256 + ((r0 + 16) ^ ((mrow & 7) << 3))] = v1;
            __syncthreads();
        }
        cur ^= 1;
    }
    const unsigned short* Xf = &XT[cur * 4096];
    const float* W; int K;
    if (m < NFR){ W = w1 + (size_t)m * IND * IND; K = IND; }
    else        { W = w2 + (size_t)(m - NFR) * IND * ONODES; K = ONODES; }
    float zsq = 0.f;
    for (int o = t; o < K; o += 512){
        float z = 0.f;
        for (int d = 0; d < 256; ++d) z += W[(size_t)d * K + o] * bf2f(Xf[d]);
        zsq += z * z;
    }
    #pragma unroll
    for (int off = 1; off < 64; off <<= 1) zsq += __shfl_xor(zsq, off);
    if (l == 0) red[8 + w] = zsq;
    float xsq = 0.f;
    if (t < 256){
        float xd = bf2f(Xf[t]);
        xsq = xd * xd;
    }
    #pragma unroll
    for (int off = 1; off < 64; off <<= 1) xsq += __shfl_xor(xsq, off);
    if (l == 0) red[16 + w] = xsq;
    __syncthreads();
    if (t == 0){
        float num = 0.f, den = 0.f;
        #pragma unroll
        for (int i = 0; i < 8; ++i){ num += red[8 + i]; den += red[16 + i]; }
        float sg = sqrtf(fmaxf(num / fmaxf(den, 1e-20f), 0.f));
        inv_s[m] = 1.0f / fmaxf(sg, 1e-6f);
    }
}

// ---------------- per-frame MLP, 2 blocks/frame (8 batches each)
__global__ __launch_bounds__(256) void kMLP(const float* __restrict__ inp, const float* __restrict__ w1,
                                            const float* __restrict__ b1, const float* __restrict__ w2,
                                            const float* __restrict__ b2, const float* __restrict__ inv_s,
                                            float* __restrict__ nf, unsigned short* __restrict__ nfb){
    int n = blockIdx.x >> 1, b0 = (blockIdx.x & 1) * 8, t = threadIdx.x;
    __shared__ float xl[8][IND];
    __shared__ float hl[8][IND];
    float i1 = inv_s[n], i2 = inv_s[NFR + n];
    for (int i = t; i < 8 * IND; i += 256){
        int b = i >> 8, d = i & 255;
        xl[b][d] = inp[(size_t)(b0 + b) * (NFR * IND) + (size_t)n * IND + d];
    }
    __syncthreads();
    const float* W1 = w1 + (size_t)n * IND * IND;
    float acc[8] = {};
    for (int d = 0; d < IND; ++d){
        float w = W1[(size_t)d * IND + t];
        #pragma unroll
        for (int b = 0; b < 8; ++b) acc[b] += xl[b][d] * w;
    }
    float bb = b1[(size_t)n * IND + t];
    #pragma unroll
    for (int b = 0; b < 8; ++b){
        float h = acc[b] * i1 + bb;
        h = 0.5f * h * (1.0f + erff(h * 0.70710678118654752f));
        hl[b][t] = h;
    }
    __syncthreads();
    const float* W2 = w2 + (size_t)n * IND * ONODES;
    float o0[8] = {}, o1[8] = {};
    for (int d = 0; d < IND; ++d){
        float wa = W2[(size_t)d * ONODES + t];
        float wb = W2[(size_t)d * ONODES + t + 256];
        #pragma unroll
        for (int b = 0; b < 8; ++b){ float h = hl[b][d]; o0[b] += h * wa; o1[b] += h * wb; }
    }
    float bb0 = b2[(size_t)n * ONODES + t], bb1 = b2[(size_t)n * ONODES + t + 256];
    #pragma unroll
    for (int b = 0; b < 8; ++b){
        float r0 = o0[b] * i2 + bb0;
        float r1 = o1[b] * i2 + bb1;
        size_t bb_ = (size_t)(b0 + b) * (ONODES * NFR);
        nf[bb_ + (size_t)t * NFR + n]         = r0;
        nf[bb_ + (size_t)(t + 256) * NFR + n] = r1;
        nfb[bb_ + (size_t)t * NFR + n]         = f2bf(r0);
        nfb[bb_ + (size_t)(t + 256) * NFR + n] = f2bf(r1);
    }
}

// ---------------- transpose wqk [128][2048] fp32 -> wqkT [2048][128] bf16
__global__ __launch_bounds__(256) void kWT(const float* __restrict__ wqk, unsigned short* __restrict__ wqkT){
    int j = blockIdx.x * 256 + threadIdx.x;
    unsigned short* dst = wqkT + (size_t)j * 128;
    #pragma unroll
    for (int fb = 0; fb < 16; ++fb){
        ushort8 v;
        #pragma unroll
        for (int u = 0; u < 8; ++u) v[u] = f2bf(wqk[(size_t)(fb * 8 + u) * 2048 + j]);
        *(ushort8*)&dst[fb * 8] = v;
    }
}

// ---------------- qk projection via SWAPPED bf16 MFMA: packed 8B stores
__global__ __launch_bounds__(256) void kQK2(const unsigned short* __restrict__ nfb,
                                            const unsigned short* __restrict__ wqkT,
                                            unsigned short* __restrict__ qb, unsigned short* __restrict__ kb){
    int b = blockIdx.x, rb = blockIdx.y, jt = blockIdx.z;
    int t = threadIdx.x, w = t >> 6, l = t & 63;
    int mrow = l & 15, kq = l >> 4;
    const unsigned short* A = nfb + ((size_t)b * 512 + rb * 64) * 128;
    const unsigned short* B = wqkT + (size_t)(jt * 512 + w * 128) * 128;
    int jbase = jt * 512 + w * 128;
    int s = jbase >> 10, c = (jbase >> 7) & 7;
    unsigned short* out = (s ? kb : qb) + ((size_t)(b * 8 + c) * 512) * 128;
    f32x4 acc[4][8];
    #pragma unroll
    for (int fi = 0; fi < 4; ++fi)
        #pragma unroll
        for (int fj = 0; fj < 8; ++fj) acc[fi][fj] = (f32x4){0.f, 0.f, 0.f, 0.f};
    #pragma unroll
    for (int kh = 0; kh < 4; ++kh){
        bf16x8 bfr[8];
        #pragma unroll
        for (int fj = 0; fj < 8; ++fj)
            bfr[fj] = *(const bf16x8*)&B[(size_t)(fj * 16 + mrow) * 128 + kh * 32 + kq * 8];
        #pragma unroll
        for (int fi = 0; fi < 4; ++fi){
            bf16x8 af = *(const bf16x8*)&A[(size_t)(fi * 16 + mrow) * 128 + kh * 32 + kq * 8];
            #pragma unroll
            for (int fj = 0; fj < 8; ++fj)
                acc[fi][fj] = __builtin_amdgcn_mfma_f32_16x16x32_bf16(bfr[fj], af, acc[fi][fj], 0, 0, 0);
        }
    }
    #pragma unroll
    for (int fi = 0; fi < 4; ++fi){
        int node = rb * 64 + fi * 16 + mrow;
        unsigned short* dst = out + (size_t)node * 128 + kq * 4;
        #pragma unroll
        for (int fj = 0; fj < 8; ++fj){
            ushort4v v;
            #pragma unroll
            for (int r = 0; r < 4; ++r) v[r] = f2bf(acc[fi][fj][r]);
            *(ushort4v*)&dst[fj * 16] = v;
        }
    }
}

// ---------------- scores via SWAPPED MFMA (K*Q^T = S^T fragments) + softmax -> attn bf16
__global__ __launch_bounds__(256) void kS2(const unsigned short* __restrict__ qb,
                                           const unsigned short* __restrict__ kb,
                                           unsigned short* __restrict__ attnb){
    int b = blockIdx.x, c = blockIdx.y, rb = blockIdx.z;
    int t = threadIdx.x, w = t >> 6, l = t & 63;
    int mrow = l & 15, kq = l >> 4;
    size_t bc = (size_t)(b * 8 + c) * 512;
    const unsigned short* Q  = qb + (bc + rb * 64) * 128;
    const unsigned short* Kp = kb + (bc + w * 128) * 128;
    __shared__ float rmax[4][64];
    __shared__ float rsum[4][64];
    f32x4 acc[4][8];
    #pragma unroll
    for (int fi = 0; fi < 4; ++fi)
        #pragma unroll
        for (int fj = 0; fj < 8; ++fj) acc[fi][fj] = (f32x4){0.f, 0.f, 0.f, 0.f};
    #pragma unroll
    for (int kh = 0; kh < 4; ++kh){
        bf16x8 kfr[8];
        #pragma unroll
        for (int fj = 0; fj < 8; ++fj)
            kfr[fj] = *(const bf16x8*)&Kp[(size_t)(fj * 16 + mrow) * 128 + kh * 32 + kq * 8];
        #pragma unroll
        for (int fi = 0; fi < 4; ++fi){
            bf16x8 qf = *(const bf16x8*)&Q[(size_t)(fi * 16 + mrow) * 128 + kh * 32 + kq * 8];
            #pragma unroll
            for (int fj = 0; fj < 8; ++fj)
                acc[fi][fj] = __builtin_amdgcn_mfma_f32_16x16x32_bf16(kfr[fj], qf, acc[fi][fj], 0, 0, 0);
        }
    }
    #pragma unroll
    for (int fi = 0; fi < 4; ++fi){
        float mx = acc[fi][0][0];
        #pragma unroll
        for (int fj = 0; fj < 8; ++fj)
            #pragma unroll
            for (int r = 0; r < 4; ++r) mx = fmaxf(mx, acc[fi][fj][r]);
        mx = fmaxf(mx, __shfl_xor(mx, 16));
        mx = fmaxf(mx, __shfl_xor(mx, 32));
        if (kq == 0) rmax[w][fi * 16 + mrow] = mx;
    }
    __syncthreads();
    #pragma unroll
    for (int fi = 0; fi < 4; ++fi){
        int ql = fi * 16 + mrow;
        float gm = fmaxf(fmaxf(rmax[0][ql], rmax[1][ql]), fmaxf(rmax[2][ql], rmax[3][ql]));
        float s = 0.f;
        #pragma unroll
        for (int fj = 0; fj < 8; ++fj)
            #pragma unroll
            for (int r = 0; r < 4; ++r){
                float p = __expf((acc[fi][fj][r] - gm) * SM_SCALE);
                acc[fi][fj][r] = p;
                s += p;
            }
        s += __shfl_xor(s, 16);
        s += __shfl_xor(s, 32);
        if (kq == 0) rsum[w][ql] = s;
    }
    __syncthreads();
    #pragma unroll
    for (int fi = 0; fi < 4; ++fi){
        int ql = fi * 16 + mrow;
        float inv = 1.0f / (rsum[0][ql] + rsum[1][ql] + rsum[2][ql] + rsum[3][ql]);
        size_t rowb = (bc + rb * 64 + ql) * 512 + w * 128 + kq * 4;
        #pragma unroll
        for (int fj = 0; fj < 8; ++fj){
            ushort4v v;
            #pragma unroll
            for (int r = 0; r < 4; ++r) v[r] = f2bf(acc[fi][fj][r] * inv);
            *(ushort4v*)&attnb[rowb + fj * 16] = v;
        }
    }
}

// ---------------- fused: channel-sum radix-select top-32 + diag -> mask -> row-normalize -> bf16 NR
__global__ __launch_bounds__(256) void kTN(const unsigned short* __restrict__ attnb, unsigned short* __restrict__ nrb){
    int b = blockIdx.x >> 9, n = blockIdx.x & 511;
    int t = threadIdx.x, w = t >> 6, lane = t & 63;
    __shared__ unsigned short al[8][512];
    __shared__ unsigned long long keepm[8];
    ushort8* alv = (ushort8*)&al[0][0];
    for (int i = t; i < 512; i += 256){
        int c = i >> 6, o = i & 63;
        alv[i] = *(const ushort8*)&attnb[((size_t)(b * 8 + c) * 512 + n) * 512 + o * 8];
    }
    __syncthreads();
    if (w == 0){
        unsigned int vb[8];
        #pragma unroll
        for (int j = 0; j < 8; ++j){
            float s = 0.f;
            #pragma unroll
            for (int c = 0; c < 8; ++c) s += bf2f(al[c][j * 64 + lane]);
            vb[j] = __float_as_uint(s);
        }
        unsigned int T = 0u;
        for (int bit = 31; bit >= 0; --bit){
            unsigned int cand = T | (1u << bit);
            int cnt = 0;
            #pragma unroll
            for (int j = 0; j < 8; ++j) cnt += __popcll(__ballot(vb[j] >= cand));
            if (cnt >= 32) T = cand;
        }
        int cntgt = 0;
        #pragma unroll
        for (int j = 0; j < 8; ++j) cntgt += __popcll(__ballot(vb[j] > T));
        int need = 32 - cntgt;
        unsigned long long lmask = (1ull << lane) - 1ull;
        int run = 0;
        #pragma unroll
        for (int j = 0; j < 8; ++j){
            bool eq = (vb[j] == T);
            unsigned long long eqm = __ballot(eq);
            int rank = run + __popcll(eqm & lmask);
            bool kv = (vb[j] > T) || (eq && rank < need);
            unsigned long long km = __ballot(kv);
            if (lane == 0) keepm[j] = km;
            run += __popcll(eqm);
        }
    }
    __syncthreads();
    #pragma unroll
    for (int cc = 0; cc < 2; ++cc){
        int c = w * 2 + cc;
        float e[8]; float rs = 0.f;
        #pragma unroll
        for (int j = 0; j < 8; ++j){
            float a = bf2f(al[c][j * 64 + lane]);
            bool keep = ((keepm[j] >> lane) & 1ull) || (j * 64 + lane == n);
            e[j] = keep ? a : 0.0f;
            rs += e[j];
        }
        #pragma unroll
        for (int off = 1; off < 64; off <<= 1) rs += __shfl_xor(rs, off);
        float inv = 1.0f / (rs + 1e-6f);
        size_t base = ((size_t)(b * 8 + c) * 512 + n) * 512;
        #pragma unroll
        for (int j = 0; j < 8; ++j) nrb[base + j * 64 + lane] = f2bf(e[j] * inv);
    }
}

// ---------------- column sums of NR (bf16 in, fp32 out), ushort8-vectorized
__global__ __launch_bounds__(1024) void kC(const unsigned short* __restrict__ nrb, float* __restrict__ cs){
    int b = blockIdx.x, c = blockIdx.y, t = threadIdx.x;
    int mg = (t & 63) * 8;
    int nh = t >> 6;
    const unsigned short* Mp = nrb + (size_t)(b * 8 + c) * 262144;
    float s[8] = {};
    for (int n = nh * 32; n < nh * 32 + 32; ++n){
        ushort8 v = *(const ushort8*)&Mp[(size_t)n * 512 + mg];
        #pragma unroll
        for (int j = 0; j < 8; ++j) s[j] += bf2f(v[j]);
    }
    __shared__ float red[16][512];
    #pragma unroll
    for (int j = 0; j < 8; ++j) red[nh][mg + j] = s[j];
    __syncthreads();
    if (t < 512){
        float tot = 0.f;
        #pragma unroll
        for (int i = 0; i < 16; ++i) tot += red[i][t];
        cs[(size_t)(b * 8 + c) * 512 + t] = tot;
    }
}

// ---------------- out = (NR*D) * NR^T per (b,c), one-sided D; swapped MFMA; 128x256 tiles.
__global__ __launch_bounds__(256, 2) void kF(const unsigned short* __restrict__ S, const float* __restrict__ cs,
                                             float* __restrict__ oe){
    int b = blockIdx.x, c = blockIdx.y, tz = blockIdx.z;
    int nb = (tz >> 1) * 128, mb = (tz & 1) * 256;
    size_t bc = (size_t)(b * 8 + c) * 512;
    const unsigned short* M = S + bc * 512;
    __shared__ unsigned short At[128 * 64];
    __shared__ unsigned short Bt[256 * 64];
    __shared__ float dl[512];
    int t = threadIdx.x;
    for (int i = t; i < 512; i += 256){ float v = cs[bc + i]; dl[i] = 1.0f / (v + 1e-6f); }
    int w = t >> 6, l = t & 63;
    int wr = (w & 1) * 64, wc = (w >> 1) * 128;
    f32x4 acc[4][8];
    #pragma unroll
    for (int fi = 0; fi < 4; ++fi)
        #pragma unroll
        for (int fj = 0; fj < 8; ++fj) acc[fi][fj] = (f32x4){0.f, 0.f, 0.f, 0.f};
    int srow = t >> 3, sg = t & 7;
    int mrow = l & 15, kq = l >> 4;
    __syncthreads();
    for (int kb = 0; kb < 512; kb += 64){
        __syncthreads();
        float4 d0 = *(const float4*)&dl[kb + sg * 8];
        float4 d1 = *(const float4*)&dl[kb + sg * 8 + 4];
        float dv[8] = {d0.x, d0.y, d0.z, d0.w, d1.x, d1.y, d1.z, d1.w};
        #pragma unroll
        for (int i = 0; i < 4; ++i){
            int row = i * 32 + srow;
            int dstg = sg ^ (row & 7);
            ushort8 va = *(const ushort8*)&M[(size_t)(nb + row) * 512 + kb + sg * 8];
            ushort8 wa;
            #pragma unroll
            for (int j = 0; j < 8; ++j) wa[j] = f2bf(bf2f(va[j]) * dv[j]);
            *(ushort8*)&At[row * 64 + dstg * 8] = wa;
        }
        #pragma unroll
        for (int i = 0; i < 8; ++i){
            int row = i * 32 + srow;
            int dstg = sg ^ (row & 7);
            ushort8 vb = *(const ushort8*)&M[(size_t)(mb + row) * 512 + kb + sg * 8];
            *(ushort8*)&Bt[row * 64 + dstg * 8] = vb;
        }
        __syncthreads();
        #pragma unroll
        for (int kh = 0; kh < 2; ++kh){
            bf16x8 af[4], bfr[8];
            #pragma unroll
            for (int fi = 0; fi < 4; ++fi){
                int row = wr + fi * 16 + mrow;
                int g = (kh * 4 + kq) ^ (row & 7);
                af[fi] = *(const bf16x8*)&At[row * 64 + g * 8];
            }
            #pragma unroll
            for (int fj = 0; fj < 8; ++fj){
                int row = wc + fj * 16 + mrow;
                int g = (kh * 4 + kq) ^ (row & 7);
                bfr[fj] = *(const bf16x8*)&Bt[row * 64 + g * 8];
            }
            #pragma unroll
            for (int fi = 0; fi < 4; ++fi)
                #pragma unroll
                for (int fj = 0; fj < 8; ++fj)
                    acc[fi][fj] = __builtin_amdgcn_mfma_f32_16x16x32_bf16(bfr[fj], af[fi], acc[fi][fj], 0, 0, 0);
        }
    }
    #pragma unroll
    for (int fi = 0; fi < 4; ++fi){
        int n = nb + wr + fi * 16 + mrow;
        float* orow = oe + (bc + n) * 512 + mb + wc + kq * 4;
        #pragma unroll
        for (int fj = 0; fj < 8; ++fj)
            *(float4*)&orow[fj * 16] = make_float4(acc[fi][fj][0], acc[fi][fj][1], acc[fi][fj][2], acc[fi][fj][3]);
    }
}

extern "C" void kernel_launch(void* const* d_in, const int* in_sizes, int n_in,
                              void* d_out, int out_size, void* d_ws, size_t ws_size,
                              hipStream_t stream) {
    const float* inp = (const float*)d_in[0];
    const float* w1  = (const float*)d_in[1];
    const float* b1  = (const float*)d_in[2];
    const float* w2  = (const float*)d_in[3];
    const float* b2  = (const float*)d_in[4];
    const float* wqk = (const float*)d_in[5];

    float* out_nf   = (float*)d_out;                       // [16][512][128]
    float* out_edge = out_nf + (size_t)16 * 512 * 128;     // [16][8][512][512]

    char* ws = (char*)d_ws;
    float* inv_s = (float*)ws;                             // 256 floats
    // region A (134 MB): q/k bf16 during kQK2/kS2, then reused as bf16 NR
    unsigned short* qb  = (unsigned short*)(ws + 4096);            // [16][8][512][128] bf16
    unsigned short* kbuf = qb + (size_t)16 * 8 * 512 * 128;        // [16][8][512][128] bf16
    unsigned short* nrb = qb;                                       // [16][8][512][512] bf16 (aliases q+k)
    // region B (134 MB): attn bf16; G/G2 alias it (dead before attn written)
    unsigned short* attnb = (unsigned short*)(ws + 4096 + (size_t)134 * 1024 * 1024);
    unsigned short* Gb  = attnb;                                    // [256][256][256] bf16 (33.5 MB)
    unsigned short* G2b = Gb + (size_t)256 * 65536;                 // [256][256][256] bf16 (33.5 MB)
    float* csum = (float*)(attnb + (size_t)16 * 8 * 512 * 512);    // [16][8][512]
    unsigned short* nfb  = (unsigned short*)(csum + (size_t)16 * 8 * 512);  // [16][512][128] bf16 (2 MB)
    unsigned short* wqkT = nfb + (size_t)16 * 512 * 128;                    // [2048][128] bf16 (0.5 MB)

    kG  <<<256, 512, 0, stream>>>(w1, w2, Gb);
    kG2 <<<256, 512, 0, stream>>>(Gb, G2b);
    kP3 <<<256, 512, 0, stream>>>(w1, w2, G2b, inv_s);
    kMLP<<<256, 256, 0, stream>>>(inp, w1, b1, w2, b2, inv_s, out_nf, nfb);
    kWT <<<8, 256, 0, stream>>>(wqk, wqkT);
    kQK2<<<dim3(16, 8, 4), 256, 0, stream>>>(nfb, wqkT, qb, kbuf);
    kS2 <<<dim3(16, 8, 8), 256, 0, stream>>>(qb, kbuf, attnb);
    kTN <<<8192, 256, 0, stream>>>(attnb, nrb);
    kC  <<<dim3(16, 8), 1024, 0, stream>>>(nrb, csum);
    kF  <<<dim3(16, 8, 8), 256, 0, stream>>>(nrb, csum, out_edge);
}